// Round 11
// baseline (170.135 us; speedup 1.0000x reference)
//
#include <hip/hip_runtime.h>
#include <hip/hip_bf16.h>
#include <cstdint>
#include <math.h>

#define S_LEN 2048
#define D_DIM 512
#define NROWS 8192           // B*S
#define NQKV  1536           // 3*512 output cols of the fused projection
#define QK_SCALE 0.04419417382415922f   // 1/sqrt(512)

typedef unsigned short u16;
typedef unsigned long long u64;
typedef __attribute__((ext_vector_type(8))) short short8;
typedef __attribute__((ext_vector_type(4))) float floatx4;

__device__ inline floatx4 mfma16(short8 a, short8 b, floatx4 c){
  return __builtin_amdgcn_mfma_f32_16x16x32_bf16(a, b, c, 0, 0, 0);
}
__device__ inline u16 f2b(float f){
  uint32_t u = __float_as_uint(f);
  u = (u + 0x7fffu + ((u >> 16) & 1u)) >> 16;
  return (u16)u;
}
__device__ inline float b2f(u16 u){ return __uint_as_float(((uint32_t)u) << 16); }
#define GLD16(g, l) __builtin_amdgcn_global_load_lds( \
    (const __attribute__((address_space(1))) void*)(g), \
    (__attribute__((address_space(3))) void*)(l), 16, 0, 0)

// ---------------------------------------------------------------- convert
__global__ void cvt_kernel(const float* __restrict__ x,
                           const float* __restrict__ Wq,
                           const float* __restrict__ Wk,
                           const float* __restrict__ Wv,
                           u16* __restrict__ xw)
{
  const int NT4 = (NROWS * D_DIM) / 4 + (NQKV * D_DIM) / 4;
  for (int i = blockIdx.x * blockDim.x + threadIdx.x; i < NT4;
       i += gridDim.x * blockDim.x) {
    int e = i * 4;
    const float* src;
    if (e < NROWS * D_DIM) {
      src = x + e;
    } else {
      int j = e - NROWS * D_DIM;
      if (j < 512 * 512)           src = Wq + j;
      else if (j < 2 * 512 * 512)  src = Wk + (j - 512 * 512);
      else                         src = Wv + (j - 2 * 512 * 512);
    }
    float4 v = *(const float4*)src;
    ushort4 o;
    o.x = f2b(v.x); o.y = f2b(v.y); o.z = f2b(v.z); o.w = f2b(v.w);
    *(ushort4*)(xw + e) = o;
  }
}

// ---------------------------------------------------------------- QKV GEMM
__launch_bounds__(256)
__global__ void qkv_gemm(const u16* __restrict__ xb,
                         const u16* __restrict__ wb,
                         const float* __restrict__ bq,
                         const float* __restrict__ bk,
                         const float* __restrict__ bv,
                         u16* __restrict__ qb,
                         u16* __restrict__ kb,
                         u16* __restrict__ vt)
{
  __shared__ alignas(16) u16 sm[2][16384];   // [buf][ A 128x64 | B 128x64 ]
  const int tid = threadIdx.x;
  const int l = tid & 63, w = tid >> 6;
  const int lr = l & 15, lg = l >> 4;
  const int wr = w >> 1, wc = w & 1;
  const int bid = blockIdx.x;
  const int xcd = bid & 7;
  const int t = bid >> 3;              // 0..95
  const int bn = t % 12, bmhi = t / 12;
  const int bm = (bmhi << 3) | xcd;    // A-panel pinned to XCD bm&7
  const int m0 = bm * 128, n0 = bn * 128;

  const u16* gA = xb + (size_t)(m0 + (tid >> 3)) * D_DIM + (tid & 7) * 8;
  const u16* gB = wb + (size_t)(n0 + (tid >> 3)) * D_DIM + (tid & 7) * 8;

#define STAGEK(BUF, KT) { \
  char* la = (char*)&sm[BUF][0] + tid * 16; \
  char* lb = (char*)&sm[BUF][8192] + tid * 16; \
  const u16* ga = gA + (KT) * 64; \
  const u16* gb = gB + (KT) * 64; \
  _Pragma("unroll") for (int jj = 0; jj < 4; jj++) { \
    GLD16(ga + (size_t)jj * 32 * D_DIM, la + jj * 4096); \
    GLD16(gb + (size_t)jj * 32 * D_DIM, lb + jj * 4096); } }

  floatx4 acc[4][4];
#pragma unroll
  for (int m = 0; m < 4; m++)
#pragma unroll
    for (int n = 0; n < 4; n++) acc[m][n] = 0.0f;

  STAGEK(0, 0)
  __syncthreads();

  for (int kt = 0; kt < 8; ++kt) {
    const int cb = kt & 1;
    if (kt < 7) STAGEK(cb ^ 1, kt + 1)
#pragma unroll
    for (int kk = 0; kk < 2; ++kk) {
      short8 a[4], bfr[4];
#pragma unroll
      for (int m = 0; m < 4; m++)
        a[m] = *(const short8*)&sm[cb][(wr * 64 + m * 16 + lr) * 64 + kk * 32 + lg * 8];
#pragma unroll
      for (int n = 0; n < 4; n++)
        bfr[n] = *(const short8*)&sm[cb][8192 + (wc * 64 + n * 16 + lr) * 64 + kk * 32 + lg * 8];
#pragma unroll
      for (int m = 0; m < 4; m++)
#pragma unroll
        for (int n = 0; n < 4; n++)
          acc[m][n] = mfma16(a[m], bfr[n], acc[m][n]);
    }
    __syncthreads();
  }
#undef STAGEK

  if (n0 < 1024) {
    const float* bias = (n0 < 512) ? bq : bk;
    u16* dst = (n0 < 512) ? qb : kb;
    const float scl = (n0 < 512) ? QK_SCALE : 1.0f;
    const int nbase = n0 & 511;
#pragma unroll
    for (int n = 0; n < 4; n++) {
      int gn = nbase + wc * 64 + n * 16 + lr;
      float bia = bias[gn];
#pragma unroll
      for (int m = 0; m < 4; m++) {
        int gm0 = m0 + wr * 64 + m * 16 + lg * 4;
#pragma unroll
        for (int r = 0; r < 4; r++)
          dst[(size_t)(gm0 + r) * D_DIM + gn] = f2b((acc[m][n][r] + bia) * scl);
      }
    }
  } else {
    const int nbase = n0 - 1024;
    const int bIdx = m0 >> 11;
    const int s0 = m0 & 2047;
    __syncthreads();
#pragma unroll
    for (int h = 0; h < 2; ++h) {
      if (wc == h) {
#pragma unroll
        for (int n = 0; n < 4; n++) {
          int lrow = n * 16 + lr;
          float bia = bv[nbase + h * 64 + lrow];
#pragma unroll
          for (int m = 0; m < 4; m++) {
            int lcol = wr * 64 + m * 16 + lg * 4;
#pragma unroll
            for (int r = 0; r < 4; r++)
              sm[0][lrow * 136 + lcol + r] = f2b(acc[m][n][r] + bia);
          }
        }
      }
      __syncthreads();
      {
        int row = tid >> 2;
        int c0 = (tid & 3) * 32;
        u16* dstp = vt + (size_t)bIdx * D_DIM * S_LEN
                       + (size_t)(nbase + h * 64 + row) * S_LEN + s0 + c0;
        const u16* srcp = &sm[0][row * 136 + c0];
#pragma unroll
        for (int jj = 0; jj < 4; jj++)
          *(short8*)(dstp + jj * 8) = *(const short8*)(srcp + jj * 8);
      }
      __syncthreads();
    }
  }
}

// ---------------------------------------------------------------- attention
// Per block (b, qt: 64 q-rows, chunk c: 128 kv). 4 waves, 256 thr.
// Phase1 (barrier-free): wave w owns kv-slice [w*32,w*32+32) x all 64q,
//   contracting D=512 with K/Q 16B fragments streamed straight from L2/L3
//   (96 pipelined loads, 128 MFMA, acc1=32 VGPR). No LDS, no barriers.
// Then exp+mask in-register -> P[64q][128kv] bf16 swizzled LDS + rsum. 1 barrier.
// Phase2: O[64q][512d] = P.V; wave owns d-slice 128; V^T frags from L2
//   under 128 MFMAs (acc2 = 128 VGPR).
// LDS 17.4KB; VGPR ~200-230 -> 2 blocks/CU. Grid 1088 (same mapping as R10).
__launch_bounds__(256)
__global__ void attn_chunk(const u16* __restrict__ qb,
                           const u16* __restrict__ kb,
                           const u16* __restrict__ vt,
                           u16* __restrict__ pOb,
                           float* __restrict__ pR)
{
  __shared__ alignas(16) u16 Pl[64][128];   // P bf16, row-swizzled
  __shared__ float rx[4][64];

  const int bid = blockIdx.x;
  const int xcd = bid & 7;
  const int b = xcd >> 1;
  const int j = (bid >> 3) * 2 + (xcd & 1);   // 0..271 within batch
  // invert j -> (qt, c): cum(2m)=m(m+1), cum(2m+1)=(m+1)^2
  int m = (int)(sqrtf((float)j + 0.25f) - 0.5f + 1e-4f);
  if (m * (m + 1) > j) --m;
  else if ((m + 1) * (m + 2) <= j) ++m;
  int qt, c;
  if (j < (m + 1) * (m + 1)) { qt = 2 * m;     c = j - m * (m + 1); }
  else                       { qt = 2 * m + 1; c = j - (m + 1) * (m + 1); }
  const int slot = b * 272 + j;

  const int tid = threadIdx.x;
  const int w = tid >> 6, l = tid & 63;
  const int lr = l & 15, lg = l >> 4;
  const int swz = (lr & 7) << 4;

  const u16* qsrc = qb + ((size_t)(b * S_LEN + qt * 64)) * D_DIM + lr * D_DIM + lg * 8;
  const u16* ksrc = kb + ((size_t)(b * S_LEN + c * 128 + w * 32)) * D_DIM + lr * D_DIM + lg * 8;

  // ---------------- Phase 1: S^T[w*32..+32][64q], D=512, frags from L2
  {
    floatx4 acc1[2][4];
#pragma unroll
    for (int tk = 0; tk < 2; ++tk)
#pragma unroll
      for (int tq = 0; tq < 4; ++tq) acc1[tk][tq] = 0.0f;

#pragma unroll
    for (int ks = 0; ks < 16; ++ks) {
      short8 kf[2], qf[4];
#pragma unroll
      for (int tk = 0; tk < 2; ++tk)
        kf[tk] = *(const short8*)(ksrc + (size_t)(tk * 16) * D_DIM + ks * 32);
#pragma unroll
      for (int tq = 0; tq < 4; ++tq)
        qf[tq] = *(const short8*)(qsrc + (size_t)(tq * 16) * D_DIM + ks * 32);
#pragma unroll
      for (int tk = 0; tk < 2; ++tk)
#pragma unroll
        for (int tq = 0; tq < 4; ++tq)
          acc1[tk][tq] = mfma16(kf[tk], qf[tq], acc1[tk][tq]);
    }

    // exp + causal mask -> P (LDS, swizzled) + per-q rsum partials
    float rs4[4] = {0.f, 0.f, 0.f, 0.f};
    const int q0 = qt * 64;
    const int kvb = c * 128 + w * 32;
#pragma unroll
    for (int tk = 0; tk < 2; ++tk)
#pragma unroll
      for (int tq = 0; tq < 4; ++tq) {
        const int qg = q0 + tq * 16 + lr;
        const int kvg = kvb + tk * 16 + lg * 4;
        float p0 = (kvg + 0 <= qg) ? __expf(acc1[tk][tq][0]) : 0.f;
        float p1 = (kvg + 1 <= qg) ? __expf(acc1[tk][tq][1]) : 0.f;
        float p2 = (kvg + 2 <= qg) ? __expf(acc1[tk][tq][2]) : 0.f;
        float p3 = (kvg + 3 <= qg) ? __expf(acc1[tk][tq][3]) : 0.f;
        ushort4 pk;
        pk.x = f2b(p0); pk.y = f2b(p1); pk.z = f2b(p2); pk.w = f2b(p3);
        rs4[tq] += b2f(pk.x) + b2f(pk.y) + b2f(pk.z) + b2f(pk.w);
        *(ushort4*)((char*)&Pl[0][0] + (tq * 16 + lr) * 256
                    + (((w * 32 + tk * 16 + lg * 4) * 2) ^ swz)) = pk;
      }
#pragma unroll
    for (int tq = 0; tq < 4; ++tq) {
      rs4[tq] += __shfl_xor(rs4[tq], 16);
      rs4[tq] += __shfl_xor(rs4[tq], 32);
    }
    if (lg == 0) {
#pragma unroll
      for (int tq = 0; tq < 4; ++tq) rx[w][tq * 16 + lr] = rs4[tq];
    }
  }
  __syncthreads();

  // ---------------- Phase 2: O[64q][512d] = P.V, wave d-slice = w*128
  floatx4 acc2[4][8];
#pragma unroll
  for (int tq = 0; tq < 4; ++tq)
#pragma unroll
    for (int td = 0; td < 8; ++td) acc2[tq][td] = 0.0f;

  {
    const u16* vsrc = vt + (size_t)b * D_DIM * S_LEN
                         + (size_t)(w * 128) * S_LEN + c * 128;
#pragma unroll
    for (int ks = 0; ks < 4; ++ks) {
      short8 pf[4], vf[8];
#pragma unroll
      for (int td = 0; td < 8; ++td)
        vf[td] = *(const short8*)(vsrc + (size_t)(td * 16 + lr) * S_LEN + ks * 32 + lg * 8);
#pragma unroll
      for (int tq = 0; tq < 4; ++tq)
        pf[tq] = *(const short8*)((char*)&Pl[0][0] + (tq * 16 + lr) * 256
                                  + ((ks * 64 + lg * 16) ^ swz));
#pragma unroll
      for (int tq = 0; tq < 4; ++tq)
#pragma unroll
        for (int td = 0; td < 8; ++td)
          acc2[tq][td] = mfma16(pf[tq], vf[td], acc2[tq][td]);
    }
  }

  // ---------------- flush partials
  {
    u16* po = pOb + (size_t)slot * (64 * 512) + w * 128;
#pragma unroll
    for (int tq = 0; tq < 4; ++tq)
#pragma unroll
      for (int r = 0; r < 4; ++r) {
        const int row = tq * 16 + lg * 4 + r;
        u16* op = po + (size_t)row * 512 + lr;
#pragma unroll
        for (int td = 0; td < 8; ++td)
          __builtin_nontemporal_store(f2b(acc2[tq][td][r]), op + td * 16);
      }
    if (tid < 64) {
      float rs = rx[0][tid] + rx[1][tid] + rx[2][tid] + rx[3][tid];
      __builtin_nontemporal_store(rs, &pR[slot * 64 + tid]);
    }
  }
}

// ---------------------------------------------------------------- reduce partials
__launch_bounds__(256)
__global__ void attn_reduce(const u16* __restrict__ pOb,
                            const float* __restrict__ pR,
                            float* __restrict__ out)
{
  const int id = blockIdx.x;            // b(2) | qt(5) | quarter(2): 512 blocks
  const int b = id >> 7;
  const int qt = (id >> 2) & 31;
  const int qu = id & 3;
  const int h = qt >> 1;
  const int nch = h + 1;
  const int base = b * 272 + (h + 1) * (h + (qt & 1));   // b*272 + cum(qt)

  const int row = threadIdx.x >> 2;                 // 0..63
  const int c0 = qu * 128 + (threadIdx.x & 3) * 32; // col start

  float rs = 0.f;
  for (int c = 0; c < nch; ++c) rs += pR[(base + c) * 64 + row];
  const float inv = 1.0f / rs;

  float acc[32];
#pragma unroll
  for (int e = 0; e < 32; ++e) acc[e] = 0.f;
  for (int c = 0; c < nch; ++c) {
    const u16* src = pOb + ((size_t)(base + c) * 64 + row) * 512 + c0;
#pragma unroll
    for (int t = 0; t < 8; ++t) {
      ushort4 v = ((const ushort4*)src)[t];
      acc[t * 4 + 0] += b2f(v.x);
      acc[t * 4 + 1] += b2f(v.y);
      acc[t * 4 + 2] += b2f(v.z);
      acc[t * 4 + 3] += b2f(v.w);
    }
  }
  float* dst = out + ((size_t)(b * S_LEN + qt * 64 + row)) * 512 + c0;
#pragma unroll
  for (int t = 0; t < 8; ++t) {
    float4 v;
    v.x = acc[t * 4 + 0] * inv;
    v.y = acc[t * 4 + 1] * inv;
    v.z = acc[t * 4 + 2] * inv;
    v.w = acc[t * 4 + 3] * inv;
    *(float4*)(dst + t * 4) = v;
  }
}

// ---------------------------------------------------------------- launch
extern "C" void kernel_launch(void* const* d_in, const int* in_sizes, int n_in,
                              void* d_out, int out_size, void* d_ws, size_t ws_size,
                              hipStream_t stream)
{
  const float* x  = (const float*)d_in[0];
  const float* Wq = (const float*)d_in[1];
  const float* bq = (const float*)d_in[2];
  const float* Wk = (const float*)d_in[3];
  const float* bk = (const float*)d_in[4];
  const float* Wv = (const float*)d_in[5];
  const float* bv = (const float*)d_in[6];
  float* out = (float*)d_out;

  u16* xw = (u16*)d_ws;
  u16* xb = xw;                              // [8192][512] bf16
  u16* wb = xb + (size_t)NROWS * D_DIM;      // [1536][512] bf16
  u16* qb = wb + (size_t)NQKV * D_DIM;       // [8192][512] bf16 (scaled)
  u16* kb = qb + (size_t)NROWS * D_DIM;      // [8192][512] bf16
  u16* vt = kb + (size_t)NROWS * D_DIM;      // [4][512][2048] bf16 (V^T)
  u16* pOb = vt + (size_t)NROWS * D_DIM;     // [1088][64][512] bf16 partial numerators
  float* pR = (float*)(pOb + (size_t)1088 * 64 * D_DIM);  // [1088][64] f32

  hipLaunchKernelGGL(cvt_kernel, dim3(2048), dim3(256), 0, stream, x, Wq, Wk, Wv, xw);
  hipLaunchKernelGGL(qkv_gemm, dim3(768), dim3(256), 0, stream,
                     xb, wb, bq, bk, bv, qb, kb, vt);
  hipLaunchKernelGGL(attn_chunk, dim3(1088), dim3(256), 0, stream,
                     qb, kb, vt, pOb, pR);
  hipLaunchKernelGGL(attn_reduce, dim3(512), dim3(256), 0, stream, pOb, pR, out);
}

// Round 12
// 114.001 us; speedup vs baseline: 1.4924x; 1.4924x over previous
//
#include <hip/hip_runtime.h>
#include <hip/hip_bf16.h>
#include <cstdint>
#include <math.h>

#define S_LEN 2048
#define D_DIM 512
#define NROWS 8192           // B*S
#define NQKV  1536           // 3*512 output cols of the fused projection
#define QK_SCALE 0.04419417382415922f   // 1/sqrt(512)

typedef unsigned short u16;
typedef unsigned long long u64;
typedef __attribute__((ext_vector_type(8))) short short8;
typedef __attribute__((ext_vector_type(4))) float floatx4;

__device__ inline floatx4 mfma16(short8 a, short8 b, floatx4 c){
  return __builtin_amdgcn_mfma_f32_16x16x32_bf16(a, b, c, 0, 0, 0);
}
__device__ inline u16 f2b(float f){
  uint32_t u = __float_as_uint(f);
  u = (u + 0x7fffu + ((u >> 16) & 1u)) >> 16;
  return (u16)u;
}
__device__ inline float b2f(u16 u){ return __uint_as_float(((uint32_t)u) << 16); }
#define GLD16(g, l) __builtin_amdgcn_global_load_lds( \
    (const __attribute__((address_space(1))) void*)(g), \
    (__attribute__((address_space(3))) void*)(l), 16, 0, 0)

// ---------------------------------------------------------------- convert
__global__ void cvt_kernel(const float* __restrict__ x,
                           const float* __restrict__ Wq,
                           const float* __restrict__ Wk,
                           const float* __restrict__ Wv,
                           u16* __restrict__ xw)
{
  const int NT4 = (NROWS * D_DIM) / 4 + (NQKV * D_DIM) / 4;
  for (int i = blockIdx.x * blockDim.x + threadIdx.x; i < NT4;
       i += gridDim.x * blockDim.x) {
    int e = i * 4;
    const float* src;
    if (e < NROWS * D_DIM) {
      src = x + e;
    } else {
      int j = e - NROWS * D_DIM;
      if (j < 512 * 512)           src = Wq + j;
      else if (j < 2 * 512 * 512)  src = Wk + (j - 512 * 512);
      else                         src = Wv + (j - 2 * 512 * 512);
    }
    float4 v = *(const float4*)src;
    ushort4 o;
    o.x = f2b(v.x); o.y = f2b(v.y); o.z = f2b(v.z); o.w = f2b(v.w);
    *(ushort4*)(xw + e) = o;
  }
}

// ---------------------------------------------------------------- QKV GEMM
__launch_bounds__(256)
__global__ void qkv_gemm(const u16* __restrict__ xb,
                         const u16* __restrict__ wb,
                         const float* __restrict__ bq,
                         const float* __restrict__ bk,
                         const float* __restrict__ bv,
                         u16* __restrict__ qb,
                         u16* __restrict__ kb,
                         u16* __restrict__ vt)
{
  __shared__ alignas(16) u16 sm[2][16384];   // [buf][ A 128x64 | B 128x64 ]
  const int tid = threadIdx.x;
  const int l = tid & 63, w = tid >> 6;
  const int lr = l & 15, lg = l >> 4;
  const int wr = w >> 1, wc = w & 1;
  const int bid = blockIdx.x;
  const int xcd = bid & 7;
  const int t = bid >> 3;              // 0..95
  const int bn = t % 12, bmhi = t / 12;
  const int bm = (bmhi << 3) | xcd;    // A-panel pinned to XCD bm&7
  const int m0 = bm * 128, n0 = bn * 128;

  const u16* gA = xb + (size_t)(m0 + (tid >> 3)) * D_DIM + (tid & 7) * 8;
  const u16* gB = wb + (size_t)(n0 + (tid >> 3)) * D_DIM + (tid & 7) * 8;

#define STAGEK(BUF, KT) { \
  char* la = (char*)&sm[BUF][0] + tid * 16; \
  char* lb = (char*)&sm[BUF][8192] + tid * 16; \
  const u16* ga = gA + (KT) * 64; \
  const u16* gb = gB + (KT) * 64; \
  _Pragma("unroll") for (int jj = 0; jj < 4; jj++) { \
    GLD16(ga + (size_t)jj * 32 * D_DIM, la + jj * 4096); \
    GLD16(gb + (size_t)jj * 32 * D_DIM, lb + jj * 4096); } }

  floatx4 acc[4][4];
#pragma unroll
  for (int m = 0; m < 4; m++)
#pragma unroll
    for (int n = 0; n < 4; n++) acc[m][n] = 0.0f;

  STAGEK(0, 0)
  __syncthreads();

  for (int kt = 0; kt < 8; ++kt) {
    const int cb = kt & 1;
    if (kt < 7) STAGEK(cb ^ 1, kt + 1)
#pragma unroll
    for (int kk = 0; kk < 2; ++kk) {
      short8 a[4], bfr[4];
#pragma unroll
      for (int m = 0; m < 4; m++)
        a[m] = *(const short8*)&sm[cb][(wr * 64 + m * 16 + lr) * 64 + kk * 32 + lg * 8];
#pragma unroll
      for (int n = 0; n < 4; n++)
        bfr[n] = *(const short8*)&sm[cb][8192 + (wc * 64 + n * 16 + lr) * 64 + kk * 32 + lg * 8];
#pragma unroll
      for (int m = 0; m < 4; m++)
#pragma unroll
        for (int n = 0; n < 4; n++)
          acc[m][n] = mfma16(a[m], bfr[n], acc[m][n]);
    }
    __syncthreads();
  }
#undef STAGEK

  if (n0 < 1024) {
    const float* bias = (n0 < 512) ? bq : bk;
    u16* dst = (n0 < 512) ? qb : kb;
    const float scl = (n0 < 512) ? QK_SCALE : 1.0f;
    const int nbase = n0 & 511;
#pragma unroll
    for (int n = 0; n < 4; n++) {
      int gn = nbase + wc * 64 + n * 16 + lr;
      float bia = bias[gn];
#pragma unroll
      for (int m = 0; m < 4; m++) {
        int gm0 = m0 + wr * 64 + m * 16 + lg * 4;
#pragma unroll
        for (int r = 0; r < 4; r++)
          dst[(size_t)(gm0 + r) * D_DIM + gn] = f2b((acc[m][n][r] + bia) * scl);
      }
    }
  } else {
    const int nbase = n0 - 1024;
    const int bIdx = m0 >> 11;
    const int s0 = m0 & 2047;
    __syncthreads();
#pragma unroll
    for (int h = 0; h < 2; ++h) {
      if (wc == h) {
#pragma unroll
        for (int n = 0; n < 4; n++) {
          int lrow = n * 16 + lr;
          float bia = bv[nbase + h * 64 + lrow];
#pragma unroll
          for (int m = 0; m < 4; m++) {
            int lcol = wr * 64 + m * 16 + lg * 4;
#pragma unroll
            for (int r = 0; r < 4; r++)
              sm[0][lrow * 136 + lcol + r] = f2b(acc[m][n][r] + bia);
          }
        }
      }
      __syncthreads();
      {
        int row = tid >> 2;
        int c0 = (tid & 3) * 32;
        u16* dstp = vt + (size_t)bIdx * D_DIM * S_LEN
                       + (size_t)(nbase + h * 64 + row) * S_LEN + s0 + c0;
        const u16* srcp = &sm[0][row * 136 + c0];
#pragma unroll
        for (int jj = 0; jj < 4; jj++)
          *(short8*)(dstp + jj * 8) = *(const short8*)(srcp + jj * 8);
      }
      __syncthreads();
    }
  }
}

// ---------------------------------------------------------------- S = exp(K.Q^T) GEMM
// One block per lower-tri 128x128 tile (qt,kt), kt<=qt, per batch: 136 tiles,
// 544 blocks, batch pinned to XCD pair. m97 double-buffered loop, A=K (m=k,
// register-contiguous for u64-packed P stores), B=Q (n=q). Epilogue:
// exp + causal mask (diag tile only), P[b][q][2048] bf16, per-tile rowsum
// partials -> pRS[b*2048+q][kt*2+wr] (deterministic, no atomics).
__launch_bounds__(256)
__global__ void s_gemm(const u16* __restrict__ qb,
                       const u16* __restrict__ kb,
                       u16* __restrict__ P,
                       float* __restrict__ pRS)
{
  __shared__ alignas(16) u16 sm[2][16384];
  const int tid = threadIdx.x;
  const int l = tid & 63, w = tid >> 6;
  const int lr = l & 15, lg = l >> 4;
  const int wr = w >> 1, wc = w & 1;
  const int bid = blockIdx.x;
  const int xcd = bid & 7;
  const int b = xcd >> 1;
  const int j = (bid >> 3) * 2 + (xcd & 1);   // 0..135
  float g = sqrtf(8.f * (float)j + 1.f);
  int qt = (int)((g - 1.f) * 0.5f + 1e-4f);
  while ((qt + 1) * (qt + 2) / 2 <= j) ++qt;
  while (qt * (qt + 1) / 2 > j) --qt;
  const int kt = j - qt * (qt + 1) / 2;

  const u16* gA = kb + ((size_t)(b * S_LEN + kt * 128 + (tid >> 3))) * D_DIM + (tid & 7) * 8;
  const u16* gB = qb + ((size_t)(b * S_LEN + qt * 128 + (tid >> 3))) * D_DIM + (tid & 7) * 8;

#define STAGES(BUF, KT) { \
  char* la = (char*)&sm[BUF][0] + tid * 16; \
  char* lb = (char*)&sm[BUF][8192] + tid * 16; \
  const u16* ga = gA + (KT) * 64; \
  const u16* gb = gB + (KT) * 64; \
  _Pragma("unroll") for (int jj = 0; jj < 4; jj++) { \
    GLD16(ga + (size_t)jj * 32 * D_DIM, la + jj * 4096); \
    GLD16(gb + (size_t)jj * 32 * D_DIM, lb + jj * 4096); } }

  floatx4 acc[4][4];
#pragma unroll
  for (int m = 0; m < 4; m++)
#pragma unroll
    for (int n = 0; n < 4; n++) acc[m][n] = 0.0f;

  STAGES(0, 0)
  __syncthreads();
  for (int ks = 0; ks < 8; ++ks) {
    const int cb = ks & 1;
    if (ks < 7) STAGES(cb ^ 1, ks + 1)
#pragma unroll
    for (int kk = 0; kk < 2; ++kk) {
      short8 a[4], bfr[4];
#pragma unroll
      for (int m = 0; m < 4; m++)
        a[m] = *(const short8*)&sm[cb][(wr * 64 + m * 16 + lr) * 64 + kk * 32 + lg * 8];
#pragma unroll
      for (int n = 0; n < 4; n++)
        bfr[n] = *(const short8*)&sm[cb][8192 + (wc * 64 + n * 16 + lr) * 64 + kk * 32 + lg * 8];
#pragma unroll
      for (int m = 0; m < 4; m++)
#pragma unroll
        for (int n = 0; n < 4; n++)
          acc[m][n] = mfma16(a[m], bfr[n], acc[m][n]);
    }
    __syncthreads();
  }
#undef STAGES

  // epilogue: exp + mask, u64-packed P stores, rowsum partials
  const bool diag = (kt == qt);
  u16* Pb = P + (size_t)b * S_LEN * S_LEN;
#pragma unroll
  for (int n = 0; n < 4; ++n) {
    const int q = qt * 128 + wc * 64 + n * 16 + lr;
    float rs = 0.f;
#pragma unroll
    for (int m = 0; m < 4; ++m) {
      const int kb0 = kt * 128 + wr * 64 + m * 16 + lg * 4;
      u16 h[4];
#pragma unroll
      for (int r = 0; r < 4; ++r) {
        float e = __expf(acc[m][n][r]);
        if (diag && (kb0 + r > q)) e = 0.f;
        h[r] = f2b(e);
        rs += b2f(h[r]);
      }
      u64 pk = (u64)h[0] | ((u64)h[1] << 16) | ((u64)h[2] << 32) | ((u64)h[3] << 48);
      *(u64*)(Pb + (size_t)q * S_LEN + kb0) = pk;
    }
    rs += __shfl_xor(rs, 16);
    rs += __shfl_xor(rs, 32);
    if (lg == 0)
      pRS[(size_t)(b * S_LEN + q) * 32 + kt * 2 + wr] = rs;
  }
}

// ---------------------------------------------------------------- O = (P.V)/rsum
// Block: (b, pair p, dhalf). Covers q-tiles p*32 and (63-p)*32 sequentially
// (uniform 65 k-steps total), 256 d-cols (dhalf*256), 4 waves x 64d.
// A=V^T rows (m=d, f32x4 out quads contiguous), B=P rows (n=q). V^T and P
// frags streamed from XCD-pinned L2 with one-step-ahead register dbuf.
__launch_bounds__(256)
__global__ void pv_gemm(const u16* __restrict__ P,
                        const float* __restrict__ pRS,
                        const u16* __restrict__ vt,
                        float* __restrict__ out)
{
  __shared__ float rinv[64];
  const int bid = blockIdx.x;
  const int xcd = bid & 7;
  const int b = xcd >> 1;
  const int dhalf = xcd & 1;
  const int p = bid >> 3;              // 0..31
  const int q0A = p * 32, q0B = (63 - p) * 32;

  const int tid = threadIdx.x;
  const int w = tid >> 6, l = tid & 63;
  const int lr = l & 15, lg = l >> 4;
  const int d0 = dhalf * 256 + w * 64;

  const u16* Pb  = P  + (size_t)b * S_LEN * S_LEN;
  const u16* vtb = vt + (size_t)b * D_DIM * S_LEN;

  // rsum prologue: rinv[0..31] = segA rows, rinv[32..63] = segB rows
  {
    const int qi = tid >> 2;           // 0..63
    const int qrow = (qi < 32) ? q0A + qi : q0B + (qi - 32);
    const int ns = ((qrow >> 7) + 1) * 2;
    float s = 0.f;
    for (int ss = tid & 3; ss < ns; ss += 4)
      s += pRS[(size_t)(b * S_LEN + qrow) * 32 + ss];
    s += __shfl_xor(s, 1);
    s += __shfl_xor(s, 2);
    if ((tid & 3) == 0) rinv[qi] = 1.0f / s;
  }
  __syncthreads();

  auto segment = [&](int q0, int nkt, int segoff) {
    floatx4 acc[4][2];
#pragma unroll
    for (int m = 0; m < 4; ++m) { acc[m][0] = 0.0f; acc[m][1] = 0.0f; }

    short8 vfA[4], pfA[2], vfB[4], pfB[2];
#define LOADF(VF, PF, KV) { \
  _Pragma("unroll") for (int m = 0; m < 4; ++m) \
    VF[m] = *(const short8*)(vtb + (size_t)(d0 + m * 16 + lr) * S_LEN + (KV) * 32 + lg * 8); \
  _Pragma("unroll") for (int n = 0; n < 2; ++n) \
    PF[n] = *(const short8*)(Pb + (size_t)(q0 + n * 16 + lr) * S_LEN + (KV) * 32 + lg * 8); }
#define MM(VF, PF) { \
  _Pragma("unroll") for (int m = 0; m < 4; ++m) \
  _Pragma("unroll") for (int n = 0; n < 2; ++n) \
    acc[m][n] = mfma16(VF[m], PF[n], acc[m][n]); }

    LOADF(vfA, pfA, 0)
    int kv = 0;
    while (kv < nkt) {
      { const int n1 = (kv + 1 < nkt) ? kv + 1 : kv;
        LOADF(vfB, pfB, n1) }
      MM(vfA, pfA)
      ++kv;
      if (kv >= nkt) break;
      { const int n2 = (kv + 1 < nkt) ? kv + 1 : kv;
        LOADF(vfA, pfA, n2) }
      MM(vfB, pfB)
      ++kv;
    }
#undef LOADF
#undef MM

    // epilogue: normalize + write f32 out (d-contiguous float4)
#pragma unroll
    for (int n = 0; n < 2; ++n) {
      const int q = q0 + n * 16 + lr;
      const float inv = rinv[segoff + n * 16 + lr];
#pragma unroll
      for (int m = 0; m < 4; ++m) {
        const int d = d0 + m * 16 + lg * 4;
        float4 v;
        v.x = acc[m][n][0] * inv;
        v.y = acc[m][n][1] * inv;
        v.z = acc[m][n][2] * inv;
        v.w = acc[m][n][3] * inv;
        *(float4*)(out + (size_t)(b * S_LEN + q) * D_DIM + d) = v;
      }
    }
  };

  segment(q0A, p + 1, 0);
  segment(q0B, 64 - p, 32);
}

// ---------------------------------------------------------------- launch
extern "C" void kernel_launch(void* const* d_in, const int* in_sizes, int n_in,
                              void* d_out, int out_size, void* d_ws, size_t ws_size,
                              hipStream_t stream)
{
  const float* x  = (const float*)d_in[0];
  const float* Wq = (const float*)d_in[1];
  const float* bq = (const float*)d_in[2];
  const float* Wk = (const float*)d_in[3];
  const float* bk = (const float*)d_in[4];
  const float* Wv = (const float*)d_in[5];
  const float* bv = (const float*)d_in[6];
  float* out = (float*)d_out;

  u16* xw = (u16*)d_ws;
  u16* xb = xw;                              // [8192][512] bf16
  u16* wb = xb + (size_t)NROWS * D_DIM;      // [1536][512] bf16
  u16* qb = wb + (size_t)NQKV * D_DIM;       // [8192][512] bf16 (scaled)
  u16* kb = qb + (size_t)NROWS * D_DIM;      // [8192][512] bf16
  u16* vt = kb + (size_t)NROWS * D_DIM;      // [4][512][2048] bf16 (V^T)
  u16* P  = vt + (size_t)NROWS * D_DIM;      // [4][2048][2048] bf16 (exp scores)
  float* pRS = (float*)(P + (size_t)4 * S_LEN * S_LEN);  // [8192][32] f32 rowsum partials

  hipLaunchKernelGGL(cvt_kernel, dim3(2048), dim3(256), 0, stream, x, Wq, Wk, Wv, xw);
  hipLaunchKernelGGL(qkv_gemm, dim3(768), dim3(256), 0, stream,
                     xb, wb, bq, bk, bv, qb, kb, vt);
  hipLaunchKernelGGL(s_gemm, dim3(544), dim3(256), 0, stream, qb, kb, P, pRS);
  hipLaunchKernelGGL(pv_gemm, dim3(256), dim3(256), 0, stream, P, pRS, vt, out);
}

// Round 13
// 92.926 us; speedup vs baseline: 1.8309x; 1.2268x over previous
//
#include <hip/hip_runtime.h>
#include <hip/hip_bf16.h>
#include <cstdint>
#include <math.h>

#define S_LEN 2048
#define D_DIM 512
#define NROWS 8192           // B*S
#define NQKV  1536           // 3*512 output cols of the fused projection
#define QK_SCALE 0.04419417382415922f   // 1/sqrt(512)

typedef unsigned short u16;
typedef unsigned long long u64;
typedef __attribute__((ext_vector_type(8))) short short8;
typedef __attribute__((ext_vector_type(4))) float floatx4;

__device__ inline floatx4 mfma16(short8 a, short8 b, floatx4 c){
  return __builtin_amdgcn_mfma_f32_16x16x32_bf16(a, b, c, 0, 0, 0);
}
__device__ inline u16 f2b(float f){
  uint32_t u = __float_as_uint(f);
  u = (u + 0x7fffu + ((u >> 16) & 1u)) >> 16;
  return (u16)u;
}
__device__ inline float b2f(u16 u){ return __uint_as_float(((uint32_t)u) << 16); }
#define GLD16(g, l) __builtin_amdgcn_global_load_lds( \
    (const __attribute__((address_space(1))) void*)(g), \
    (__attribute__((address_space(3))) void*)(l), 16, 0, 0)

// ---------------------------------------------------------------- convert
__global__ void cvt_kernel(const float* __restrict__ x,
                           const float* __restrict__ Wq,
                           const float* __restrict__ Wk,
                           const float* __restrict__ Wv,
                           u16* __restrict__ xw)
{
  const int NT4 = (NROWS * D_DIM) / 4 + (NQKV * D_DIM) / 4;
  for (int i = blockIdx.x * blockDim.x + threadIdx.x; i < NT4;
       i += gridDim.x * blockDim.x) {
    int e = i * 4;
    const float* src;
    if (e < NROWS * D_DIM) {
      src = x + e;
    } else {
      int j = e - NROWS * D_DIM;
      if (j < 512 * 512)           src = Wq + j;
      else if (j < 2 * 512 * 512)  src = Wk + (j - 512 * 512);
      else                         src = Wv + (j - 2 * 512 * 512);
    }
    float4 v = *(const float4*)src;
    ushort4 o;
    o.x = f2b(v.x); o.y = f2b(v.y); o.z = f2b(v.z); o.w = f2b(v.w);
    *(ushort4*)(xw + e) = o;
  }
}

// ---------------------------------------------------------------- QKV GEMM
__launch_bounds__(256)
__global__ void qkv_gemm(const u16* __restrict__ xb,
                         const u16* __restrict__ wb,
                         const float* __restrict__ bq,
                         const float* __restrict__ bk,
                         const float* __restrict__ bv,
                         u16* __restrict__ qb,
                         u16* __restrict__ kb,
                         u16* __restrict__ vt)
{
  __shared__ alignas(16) u16 sm[2][16384];   // [buf][ A 128x64 | B 128x64 ]
  const int tid = threadIdx.x;
  const int l = tid & 63, w = tid >> 6;
  const int lr = l & 15, lg = l >> 4;
  const int wr = w >> 1, wc = w & 1;
  const int bid = blockIdx.x;
  const int xcd = bid & 7;
  const int t = bid >> 3;              // 0..95
  const int bn = t % 12, bmhi = t / 12;
  const int bm = (bmhi << 3) | xcd;    // A-panel pinned to XCD bm&7
  const int m0 = bm * 128, n0 = bn * 128;

  const u16* gA = xb + (size_t)(m0 + (tid >> 3)) * D_DIM + (tid & 7) * 8;
  const u16* gB = wb + (size_t)(n0 + (tid >> 3)) * D_DIM + (tid & 7) * 8;

#define STAGEK(BUF, KT) { \
  char* la = (char*)&sm[BUF][0] + tid * 16; \
  char* lb = (char*)&sm[BUF][8192] + tid * 16; \
  const u16* ga = gA + (KT) * 64; \
  const u16* gb = gB + (KT) * 64; \
  _Pragma("unroll") for (int jj = 0; jj < 4; jj++) { \
    GLD16(ga + (size_t)jj * 32 * D_DIM, la + jj * 4096); \
    GLD16(gb + (size_t)jj * 32 * D_DIM, lb + jj * 4096); } }

  floatx4 acc[4][4];
#pragma unroll
  for (int m = 0; m < 4; m++)
#pragma unroll
    for (int n = 0; n < 4; n++) acc[m][n] = 0.0f;

  STAGEK(0, 0)
  __syncthreads();

  for (int kt = 0; kt < 8; ++kt) {
    const int cb = kt & 1;
    if (kt < 7) STAGEK(cb ^ 1, kt + 1)
#pragma unroll
    for (int kk = 0; kk < 2; ++kk) {
      short8 a[4], bfr[4];
#pragma unroll
      for (int m = 0; m < 4; m++)
        a[m] = *(const short8*)&sm[cb][(wr * 64 + m * 16 + lr) * 64 + kk * 32 + lg * 8];
#pragma unroll
      for (int n = 0; n < 4; n++)
        bfr[n] = *(const short8*)&sm[cb][8192 + (wc * 64 + n * 16 + lr) * 64 + kk * 32 + lg * 8];
#pragma unroll
      for (int m = 0; m < 4; m++)
#pragma unroll
        for (int n = 0; n < 4; n++)
          acc[m][n] = mfma16(a[m], bfr[n], acc[m][n]);
    }
    __syncthreads();
  }
#undef STAGEK

  if (n0 < 1024) {
    const float* bias = (n0 < 512) ? bq : bk;
    u16* dst = (n0 < 512) ? qb : kb;
    const float scl = (n0 < 512) ? QK_SCALE : 1.0f;
    const int nbase = n0 & 511;
#pragma unroll
    for (int n = 0; n < 4; n++) {
      int gn = nbase + wc * 64 + n * 16 + lr;
      float bia = bias[gn];
#pragma unroll
      for (int m = 0; m < 4; m++) {
        int gm0 = m0 + wr * 64 + m * 16 + lg * 4;
#pragma unroll
        for (int r = 0; r < 4; r++)
          dst[(size_t)(gm0 + r) * D_DIM + gn] = f2b((acc[m][n][r] + bia) * scl);
      }
    }
  } else {
    const int nbase = n0 - 1024;
    const int bIdx = m0 >> 11;
    const int s0 = m0 & 2047;
    __syncthreads();
#pragma unroll
    for (int h = 0; h < 2; ++h) {
      if (wc == h) {
#pragma unroll
        for (int n = 0; n < 4; n++) {
          int lrow = n * 16 + lr;
          float bia = bv[nbase + h * 64 + lrow];
#pragma unroll
          for (int m = 0; m < 4; m++) {
            int lcol = wr * 64 + m * 16 + lg * 4;
#pragma unroll
            for (int r = 0; r < 4; r++)
              sm[0][lrow * 136 + lcol + r] = f2b(acc[m][n][r] + bia);
          }
        }
      }
      __syncthreads();
      {
        int row = tid >> 2;
        int c0 = (tid & 3) * 32;
        u16* dstp = vt + (size_t)bIdx * D_DIM * S_LEN
                       + (size_t)(nbase + h * 64 + row) * S_LEN + s0 + c0;
        const u16* srcp = &sm[0][row * 136 + c0];
#pragma unroll
        for (int jj = 0; jj < 4; jj++)
          *(short8*)(dstp + jj * 8) = *(const short8*)(srcp + jj * 8);
      }
      __syncthreads();
    }
  }
}

// ---------------------------------------------------------------- S = exp(K.Q^T) GEMM
__launch_bounds__(256)
__global__ void s_gemm(const u16* __restrict__ qb,
                       const u16* __restrict__ kb,
                       u16* __restrict__ P,
                       float* __restrict__ pRS)
{
  __shared__ alignas(16) u16 sm[2][16384];
  const int tid = threadIdx.x;
  const int l = tid & 63, w = tid >> 6;
  const int lr = l & 15, lg = l >> 4;
  const int wr = w >> 1, wc = w & 1;
  const int bid = blockIdx.x;
  const int xcd = bid & 7;
  const int b = xcd >> 1;
  const int j = (bid >> 3) * 2 + (xcd & 1);   // 0..135
  float g = sqrtf(8.f * (float)j + 1.f);
  int qt = (int)((g - 1.f) * 0.5f + 1e-4f);
  while ((qt + 1) * (qt + 2) / 2 <= j) ++qt;
  while (qt * (qt + 1) / 2 > j) --qt;
  const int kt = j - qt * (qt + 1) / 2;

  const u16* gA = kb + ((size_t)(b * S_LEN + kt * 128 + (tid >> 3))) * D_DIM + (tid & 7) * 8;
  const u16* gB = qb + ((size_t)(b * S_LEN + qt * 128 + (tid >> 3))) * D_DIM + (tid & 7) * 8;

#define STAGES(BUF, KT) { \
  char* la = (char*)&sm[BUF][0] + tid * 16; \
  char* lb = (char*)&sm[BUF][8192] + tid * 16; \
  const u16* ga = gA + (KT) * 64; \
  const u16* gb = gB + (KT) * 64; \
  _Pragma("unroll") for (int jj = 0; jj < 4; jj++) { \
    GLD16(ga + (size_t)jj * 32 * D_DIM, la + jj * 4096); \
    GLD16(gb + (size_t)jj * 32 * D_DIM, lb + jj * 4096); } }

  floatx4 acc[4][4];
#pragma unroll
  for (int m = 0; m < 4; m++)
#pragma unroll
    for (int n = 0; n < 4; n++) acc[m][n] = 0.0f;

  STAGES(0, 0)
  __syncthreads();
  for (int ks = 0; ks < 8; ++ks) {
    const int cb = ks & 1;
    if (ks < 7) STAGES(cb ^ 1, ks + 1)
#pragma unroll
    for (int kk = 0; kk < 2; ++kk) {
      short8 a[4], bfr[4];
#pragma unroll
      for (int m = 0; m < 4; m++)
        a[m] = *(const short8*)&sm[cb][(wr * 64 + m * 16 + lr) * 64 + kk * 32 + lg * 8];
#pragma unroll
      for (int n = 0; n < 4; n++)
        bfr[n] = *(const short8*)&sm[cb][8192 + (wc * 64 + n * 16 + lr) * 64 + kk * 32 + lg * 8];
#pragma unroll
      for (int m = 0; m < 4; m++)
#pragma unroll
        for (int n = 0; n < 4; n++)
          acc[m][n] = mfma16(a[m], bfr[n], acc[m][n]);
    }
    __syncthreads();
  }
#undef STAGES

  // epilogue: exp + mask, u64-packed P stores, rowsum partials
  const bool diag = (kt == qt);
  u16* Pb = P + (size_t)b * S_LEN * S_LEN;
#pragma unroll
  for (int n = 0; n < 4; ++n) {
    const int q = qt * 128 + wc * 64 + n * 16 + lr;
    float rs = 0.f;
#pragma unroll
    for (int m = 0; m < 4; ++m) {
      const int kb0 = kt * 128 + wr * 64 + m * 16 + lg * 4;
      u16 h[4];
#pragma unroll
      for (int r = 0; r < 4; ++r) {
        float e = __expf(acc[m][n][r]);
        if (diag && (kb0 + r > q)) e = 0.f;
        h[r] = f2b(e);
        rs += b2f(h[r]);
      }
      u64 pk = (u64)h[0] | ((u64)h[1] << 16) | ((u64)h[2] << 32) | ((u64)h[3] << 48);
      *(u64*)(Pb + (size_t)q * S_LEN + kb0) = pk;
    }
    rs += __shfl_xor(rs, 16);
    rs += __shfl_xor(rs, 32);
    if (lg == 0)
      pRS[(size_t)(b * S_LEN + q) * 32 + kt * 2 + wr] = rs;
  }
}

// ---------------------------------------------------------------- O = (P.V)/rsum  (m97 structure)
// Block: (b, m-tile 128d, q-tile 64q). Grid 512 = 4b x 4m x 32qt, 2 blocks/CU.
// A = V^T[128d][BK=64kv] (16KB), B = P[64q][64kv] (8KB), double-buffered
// global_load_lds staging, one barrier per k-step. nks = qt+1 (causal),
// longest-first qt mapping so the ragged tail backfills. Epilogue: rinv
// (from pRS, prologue) * acc -> float4 f32 stores.
__launch_bounds__(256)
__global__ void pv_gemm(const u16* __restrict__ P,
                       const float* __restrict__ pRS,
                       const u16* __restrict__ vt,
                       float* __restrict__ out)
{
  __shared__ alignas(16) u16 sm[2][12288];   // A 128x64 @0 | B 64x64 @8192
  __shared__ float rinv[64];

  const int tid = threadIdx.x;
  const int l = tid & 63, w = tid >> 6;
  const int lr = l & 15, lg = l >> 4;
  const int wr = w >> 1, wc = w & 1;         // wave: 64d x 32q quadrant
  const int bid = blockIdx.x;
  const int xcd = bid & 7;
  const int b = xcd >> 1, xl = xcd & 1;
  const int t = bid >> 3;                    // 0..63
  const int m = t & 3;                       // d-tile (128)
  const int qraw = ((t >> 2) << 1) | xl;     // 0..31
  const int qt = 31 - qraw;                  // longest first
  const int m0 = m * 128;
  const int q0 = qt * 64;
  const int nks = qt + 1;                    // BK=64 k-steps

  const u16* gA = vt + (size_t)b * D_DIM * S_LEN
                     + (size_t)(m0 + (tid >> 3)) * S_LEN + (tid & 7) * 8;
  const u16* gB = P + (size_t)b * S_LEN * S_LEN
                    + (size_t)(q0 + (tid >> 3)) * S_LEN + (tid & 7) * 8;

  // rsum prologue
  {
    const int qi = tid >> 2;                 // 0..63
    const int qrow = q0 + qi;
    const int ns = ((qrow >> 7) + 1) * 2;
    float s = 0.f;
    for (int ss = tid & 3; ss < ns; ss += 4)
      s += pRS[(size_t)(b * S_LEN + qrow) * 32 + ss];
    s += __shfl_xor(s, 1);
    s += __shfl_xor(s, 2);
    if ((tid & 3) == 0) rinv[qi] = 1.0f / s;
  }

#define STAGEPV(BUF, KS) { \
  char* la = (char*)&sm[BUF][0] + tid * 16; \
  char* lb = (char*)&sm[BUF][8192] + tid * 16; \
  const u16* ga = gA + (KS) * 64; \
  const u16* gb = gB + (KS) * 64; \
  _Pragma("unroll") for (int jj = 0; jj < 4; jj++) \
    GLD16(ga + (size_t)jj * 32 * S_LEN, la + jj * 4096); \
  _Pragma("unroll") for (int jj = 0; jj < 2; jj++) \
    GLD16(gb + (size_t)jj * 32 * S_LEN, lb + jj * 4096); }

  floatx4 acc[4][2];
#pragma unroll
  for (int mm = 0; mm < 4; mm++) { acc[mm][0] = 0.0f; acc[mm][1] = 0.0f; }

  STAGEPV(0, 0)
  __syncthreads();
  for (int ks = 0; ks < nks; ++ks) {
    const int cb = ks & 1;
    if (ks < nks - 1) STAGEPV(cb ^ 1, ks + 1)
#pragma unroll
    for (int kk = 0; kk < 2; ++kk) {
      short8 a[4], bfr[2];
#pragma unroll
      for (int mm = 0; mm < 4; mm++)
        a[mm] = *(const short8*)&sm[cb][(wr * 64 + mm * 16 + lr) * 64 + kk * 32 + lg * 8];
#pragma unroll
      for (int n = 0; n < 2; n++)
        bfr[n] = *(const short8*)&sm[cb][8192 + (wc * 32 + n * 16 + lr) * 64 + kk * 32 + lg * 8];
#pragma unroll
      for (int mm = 0; mm < 4; mm++)
#pragma unroll
        for (int n = 0; n < 2; n++)
          acc[mm][n] = mfma16(a[mm], bfr[n], acc[mm][n]);
    }
    __syncthreads();
  }
#undef STAGEPV

  // epilogue: normalize + float4 stores. d = m0+wr*64+mm*16+lg*4+r (C row),
  // q = wc*32+n*16+lr (C col).
#pragma unroll
  for (int n = 0; n < 2; ++n) {
    const int q = q0 + wc * 32 + n * 16 + lr;
    const float inv = rinv[wc * 32 + n * 16 + lr];
    float* op = out + (size_t)(b * S_LEN + q) * D_DIM + m0 + wr * 64 + lg * 4;
#pragma unroll
    for (int mm = 0; mm < 4; ++mm) {
      float4 v;
      v.x = acc[mm][n][0] * inv;
      v.y = acc[mm][n][1] * inv;
      v.z = acc[mm][n][2] * inv;
      v.w = acc[mm][n][3] * inv;
      *(float4*)(op + mm * 16) = v;
    }
  }
}

// ---------------------------------------------------------------- launch
extern "C" void kernel_launch(void* const* d_in, const int* in_sizes, int n_in,
                              void* d_out, int out_size, void* d_ws, size_t ws_size,
                              hipStream_t stream)
{
  const float* x  = (const float*)d_in[0];
  const float* Wq = (const float*)d_in[1];
  const float* bq = (const float*)d_in[2];
  const float* Wk = (const float*)d_in[3];
  const float* bk = (const float*)d_in[4];
  const float* Wv = (const float*)d_in[5];
  const float* bv = (const float*)d_in[6];
  float* out = (float*)d_out;

  u16* xw = (u16*)d_ws;
  u16* xb = xw;                              // [8192][512] bf16
  u16* wb = xb + (size_t)NROWS * D_DIM;      // [1536][512] bf16
  u16* qb = wb + (size_t)NQKV * D_DIM;       // [8192][512] bf16 (scaled)
  u16* kb = qb + (size_t)NROWS * D_DIM;      // [8192][512] bf16
  u16* vt = kb + (size_t)NROWS * D_DIM;      // [4][512][2048] bf16 (V^T)
  u16* P  = vt + (size_t)NROWS * D_DIM;      // [4][2048][2048] bf16 (exp scores)
  float* pRS = (float*)(P + (size_t)4 * S_LEN * S_LEN);  // [8192][32] f32 rowsum partials

  hipLaunchKernelGGL(cvt_kernel, dim3(2048), dim3(256), 0, stream, x, Wq, Wk, Wv, xw);
  hipLaunchKernelGGL(qkv_gemm, dim3(768), dim3(256), 0, stream,
                     xb, wb, bq, bk, bv, qb, kb, vt);
  hipLaunchKernelGGL(s_gemm, dim3(544), dim3(256), 0, stream, qb, kb, P, pRS);
  hipLaunchKernelGGL(pv_gemm, dim3(512), dim3(256), 0, stream, P, pRS, vt, out);
}